// Round 5
// baseline (424.538 us; speedup 1.0000x reference)
//
#include <hip/hip_runtime.h>
#include <hip/hip_fp16.h>
#include <stdint.h>

// Problem constants (from reference setup_inputs)
#define T_TOK 1024
#define K_IN  4096
#define N_OUT 6144
#define N_Q   4096
#define N_KV  1024
#define N_D   4
#define KP    512          // K_IN/8 packed int32 per row

// GEMM tiling
#define TM 256
#define TN 256
#define BK 64
#define KSPLIT 4
#define KCH (K_IN / KSPLIT)     // 1024
#define NSTEPS (KCH / BK)       // 16
#define PM_MAX 1792        // max padded total (sum of 256-padded segments)
#define MT (PM_MAX/TM)     // 7
#define NT (N_OUT/TN)      // 24
#define NBLK (NT * MT * KSPLIT) // 672

typedef __attribute__((ext_vector_type(8))) _Float16 half8;   // MFMA f16 A/B frag
typedef __attribute__((ext_vector_type(4))) float    float4v; // MFMA C/D frag
typedef __attribute__((ext_vector_type(4))) float    f32x4;
typedef __attribute__((ext_vector_type(4))) uint     u32x4;

__device__ __forceinline__ uint packh2(float a, float b) {
    union { __half2 h; uint u; } r;
    r.h = __halves2half2(__float2half(a), __float2half(b));
    return r.u;
}

// ---------------------------------------------------------------------------
// K1: group tokens by adapter. perm[PM_MAX] = token index or -1 (padding);
// pofs[d] = padded segment starts (multiples of TM=256), pofs[N_D] = total.
// ---------------------------------------------------------------------------
__global__ void build_perm_kernel(const int* __restrict__ indices,
                                  int* __restrict__ perm,
                                  int* __restrict__ pofs) {
    __shared__ int cnt[N_D], cur[N_D], ps[N_D + 1];
    int tid = threadIdx.x;
    if (tid < N_D) { cnt[tid] = 0; cur[tid] = 0; }
    __syncthreads();
    for (int t = tid; t < T_TOK; t += blockDim.x) atomicAdd(&cnt[indices[t]], 1);
    for (int p = tid; p < PM_MAX; p += blockDim.x) perm[p] = -1;
    __syncthreads();
    if (tid == 0) {
        int run = 0;
        for (int d = 0; d < N_D; d++) { ps[d] = run; run += ((cnt[d] + TM - 1) / TM) * TM; }
        ps[N_D] = run;
        for (int d = 0; d <= N_D; d++) pofs[d] = ps[d];
    }
    __syncthreads();
    for (int t = tid; t < T_TOK; t += blockDim.x) {
        int d = indices[t];
        int r = atomicAdd(&cur[d], 1);
        perm[ps[d] + r] = t;
    }
}

// ---------------------------------------------------------------------------
// K2: wb16 = f16(w_base). 8 elems/thread. (150 MB traffic, ~25 us)
// ---------------------------------------------------------------------------
__global__ void conv_wb_kernel(const float* __restrict__ w_base,
                               __half* __restrict__ wb16) {
    size_t id = (size_t)blockIdx.x * blockDim.x + threadIdx.x;  // [0, N_OUT*K_IN/8)
    const f32x4* src = (const f32x4*)(w_base + id * 8);
    f32x4 a = __builtin_nontemporal_load(src);
    f32x4 b = __builtin_nontemporal_load(src + 1);
    u32x4 packv;
    packv.x = packh2(a.x, a.y); packv.y = packh2(a.z, a.w);
    packv.z = packh2(b.x, b.y); packv.w = packh2(b.z, b.w);
    *(u32x4*)(wb16 + id * 8) = packv;
}

// ---------------------------------------------------------------------------
// K3: per-row delta constants: sArr[d][o] = f16(s), uArr[d][o] = f16((z+1)*s)
// ---------------------------------------------------------------------------
__global__ void scaleprep_kernel(const int* __restrict__ qz_q, const int* __restrict__ qz_k, const int* __restrict__ qz_v,
                                 const float* __restrict__ sc_q, const float* __restrict__ sc_k, const float* __restrict__ sc_v,
                                 __half* __restrict__ sArr, __half* __restrict__ uArr) {
    int id = blockIdx.x * blockDim.x + threadIdx.x;   // [0, N_D*N_OUT)
    int o  = id % N_OUT;
    int d  = id / N_OUT;
    const int* qz; const float* sc; int r, Osec;
    if (o < N_Q)            { qz = qz_q; sc = sc_q; r = o;                Osec = N_Q;  }
    else if (o < N_Q + N_KV){ qz = qz_k; sc = sc_k; r = o - N_Q;          Osec = N_KV; }
    else                    { qz = qz_v; sc = sc_v; r = o - (N_Q + N_KV); Osec = N_KV; }
    float s = sc[(size_t)d * Osec + r];
    int  zq = qz[(size_t)d * (Osec / 8) + (r >> 3)];
    int   z = (zq >> ((r & 7) * 4)) & 0xF;
    sArr[id] = __float2half(s);
    uArr[id] = __float2half((float)(z + 1) * s);
}

// ---------------------------------------------------------------------------
// K4: Xp[pm][k] = f16(x[perm[pm]][k]) or 0 for padding rows.
// ---------------------------------------------------------------------------
__global__ void build_xp_kernel(const float* __restrict__ x,
                                const int* __restrict__ perm,
                                __half* __restrict__ xp) {
    int pm = blockIdx.x;
    int c0 = blockIdx.y * 2048 + threadIdx.x * 8;
    int tok = perm[pm];
    u32x4 packv;
    if (tok < 0) {
        packv.x = packv.y = packv.z = packv.w = 0;
    } else {
        const f32x4* src = (const f32x4*)(x + (size_t)tok * K_IN + c0);
        f32x4 a = __builtin_nontemporal_load(src);
        f32x4 b = __builtin_nontemporal_load(src + 1);
        packv.x = packh2(a.x, a.y); packv.y = packh2(a.z, a.w);
        packv.z = packh2(b.x, b.y); packv.w = packh2(b.z, b.w);
    }
    *(u32x4*)(xp + (size_t)pm * K_IN + c0) = packv;
}

// ---------------------------------------------------------------------------
// K5: out[t][n] = bias[n] (split-K accumulators atomicAdd on top).
// ---------------------------------------------------------------------------
__global__ void init_out_kernel(const float* __restrict__ bias,
                                float* __restrict__ out) {
    int id = blockIdx.x * blockDim.x + threadIdx.x;     // [0, T*N_OUT/4)
    int n4 = id & (N_OUT / 4 - 1);                      // N_OUT/4 = 1536
    int t  = id / (N_OUT / 4);
    float4 b = *(const float4*)(bias + n4 * 4);
    *(float4*)(out + (size_t)t * N_OUT + n4 * 4) = b;
}

// ---------------------------------------------------------------------------
// dequant: 8 nibbles of q -> f16 via 0x6400 trick; W = (qf-1024)*s + (wb - u)
// u = (z+1)*s per row. All pk-f16 math; exact error ~2e-4 per weight.
// ---------------------------------------------------------------------------
__device__ __forceinline__ half8 dq8(uint q, half8 wbf, __half2 s2, __half2 u2, __half2 h1024) {
    union { half8 v; uint u[4]; } in, out;
    in.v = wbf;
    uint p[4];
    p[0] = (q & 0xFu)         | ((q << 12) & 0xF0000u) | 0x64006400u;
    p[1] = ((q >> 8) & 0xFu)  | ((q << 4)  & 0xF0000u) | 0x64006400u;
    p[2] = ((q >> 16) & 0xFu) | ((q >> 4)  & 0xF0000u) | 0x64006400u;
    p[3] = ((q >> 24) & 0xFu) | ((q >> 12) & 0xF0000u) | 0x64006400u;
#pragma unroll
    for (int i = 0; i < 4; i++) {
        union { uint u; __half2 h; } qa, wa, ra;
        qa.u = p[i]; wa.u = in.u[i];
        ra.h = __hfma2(__hsub2(qa.h, h1024), s2, __hsub2(wa.h, u2));
        out.u[i] = ra.u;
    }
    return out.v;
}

// ---------------------------------------------------------------------------
// K6: fused split-K GEMM with on-the-fly delta dequant.
// out[perm[m]][n] += Xp[m] @ (wb16[n] + dequant(qw[d(m)][n]))^T  (K-chunk kz)
// 256x256 tile, 512 thr (8 waves of 64x128), BK=64, dbuf LDS 144 KB:
// A 32K + WB 32K + QW-packed 8K per stage. All B info staged is 40 KB/step
// (vs 64 KB bf16 wall) and LLC-resident (~110 MB working set).
// ---------------------------------------------------------------------------
__global__ __launch_bounds__(512, 2) void gemm_kernel(
    const __half* __restrict__ xp, const __half* __restrict__ wb16,
    const int* __restrict__ qw_q, const int* __restrict__ qw_k, const int* __restrict__ qw_v,
    const __half* __restrict__ sArr, const __half* __restrict__ uArr,
    const int* __restrict__ perm, const int* __restrict__ pofs,
    float* __restrict__ out) {

    __shared__ __half As[2][TM * BK];   // 2 x 32 KB
    __shared__ __half Ws[2][TN * BK];   // 2 x 32 KB
    __shared__ int    Qs[2][TN * 8];    // 2 x 8 KB

    // XCD-pinned decode: bn%8 == lin%8
    int lin  = blockIdx.x;
    int low3 = lin & 7, rest = lin >> 3;
    int j    = rest % (MT * KSPLIT), bq = rest / (MT * KSPLIT);
    int bn   = bq * 8 + low3;            // [0,24)
    int bm   = j % MT, kz = j / MT;

    int m0 = bm * TM, n0 = bn * TN;
    int ptot = pofs[N_D];
    if (m0 >= ptot) return;                       // uniform per block
    int d = 0;
    while (d < N_D - 1 && m0 >= pofs[d + 1]) d++; // tile fully inside segment d

    // qw section select (TN=256 tiles never straddle q/k/v boundaries)
    const int* qwsec; int r0;
    if (n0 < N_Q)             { qwsec = qw_q + (size_t)d * N_Q  * KP; r0 = n0; }
    else if (n0 < N_Q + N_KV) { qwsec = qw_k + (size_t)d * N_KV * KP; r0 = n0 - N_Q; }
    else                      { qwsec = qw_v + (size_t)d * N_KV * KP; r0 = n0 - (N_Q + N_KV); }
    const __half* sSec = sArr + (size_t)d * N_OUT + n0;
    const __half* uSec = uArr + (size_t)d * N_OUT + n0;

    int tid  = threadIdx.x;
    int lane = tid & 63;
    int wv   = tid >> 6;                 // 8 waves
    int wm   = (wv & 3) * 64;            // 4 row groups x 64
    int wn   = (wv >> 2) * 128;          // 2 col groups x 128
    int quad = lane >> 4;
    int l16  = lane & 15;
    int xa   = l16 & 7;                  // read-side swizzle term

    const __half2 h1024 = __half2half2(__float2half(1024.0f));

    // per-lane scale constants for the 8 B-row groups this lane touches
    __half2 s2[8], u2[8];
#pragma unroll
    for (int jj = 0; jj < 8; jj++) {
        int r = wn + jj * 16 + l16;
        s2[jj] = __half2half2(sSec[r]);
        u2[jj] = __half2half2(uSec[r]);
    }

    const float4v zero4 = {0.f, 0.f, 0.f, 0.f};
    float4v acc[4][8];
#pragma unroll
    for (int i = 0; i < 4; i++)
#pragma unroll
        for (int jj = 0; jj < 8; jj++) acc[i][jj] = zero4;

    auto gll = [](const void* g, void* l) {
        __builtin_amdgcn_global_load_lds((const __attribute__((address_space(1))) void*)g,
                                         (__attribute__((address_space(3))) void*)l, 16, 0, 0);
    };

    // stage one BK-tile: A (256x64 f16), WB (256x64 f16), QW (256x8 int32)
    auto stage = [&](int buf, int k0) {
        __half* dA = As[buf]; __half* dW = Ws[buf]; int* dQ = Qs[buf];
#pragma unroll
        for (int w = 0; w < 4; w++) {
            int p   = w * 512 + tid;
            int row = p >> 3;                       // [0,256)
            int ckl = (p & 7) ^ (row & 7);          // XOR swizzle
            int base = (w * 512 + (tid & ~63)) * 8; // wave-uniform half offset
            gll(xp   + (size_t)(m0 + row) * K_IN + k0 + ckl * 8, dA + base);
            gll(wb16 + (size_t)(n0 + row) * K_IN + k0 + ckl * 8, dW + base);
        }
        {
            int row = tid >> 1, hf = tid & 1;       // 2 lanes/row, 16B each
            gll(qwsec + (size_t)(r0 + row) * KP + (k0 >> 3) + hf * 4,
                dQ + (size_t)(tid & ~63) * 4);
        }
    };

    int kbase = kz * KCH;
    int buf = 0;
    stage(0, kbase);
    __syncthreads();

    for (int s = 0; s < NSTEPS; s++) {
        if (s + 1 < NSTEPS) stage(1 - buf, kbase + (s + 1) * BK);

        const __half* Ab = As[buf];
        const __half* Wb = Ws[buf];
        const int*    Qb = Qs[buf];
#pragma unroll
        for (int kk = 0; kk < BK; kk += 32) {
            int ckb = (kk >> 3) + quad;      // 16B-chunk column wanted
            half8 a[4];
#pragma unroll
            for (int i = 0; i < 4; i++)
                a[i] = *(const half8*)(Ab + (wm + i * 16 + l16) * BK + (ckb ^ xa) * 8);
#pragma unroll
            for (int jj = 0; jj < 8; jj++) {
                int   r   = wn + jj * 16 + l16;
                half8 wbf = *(const half8*)(Wb + r * BK + (ckb ^ xa) * 8);
                uint  q   = (uint)Qb[r * 8 + ckb];
                half8 b   = dq8(q, wbf, s2[jj], u2[jj], h1024);
#pragma unroll
                for (int i = 0; i < 4; i++)
                    acc[i][jj] = __builtin_amdgcn_mfma_f32_16x16x32_f16(a[i], b, acc[i][jj], 0, 0, 0);
            }
        }
        __syncthreads();   // drains next tile's loads + protects buf for re-stage
        buf ^= 1;
    }

    // epilogue: C/D layout col = lane&15, row = quad*4 + reg  [m89/m91 verified]
#pragma unroll
    for (int i = 0; i < 4; i++) {
        int toks[4];
#pragma unroll
        for (int r = 0; r < 4; r++) toks[r] = perm[m0 + wm + i * 16 + quad * 4 + r];
#pragma unroll
        for (int jj = 0; jj < 8; jj++) {
            int col = n0 + wn + jj * 16 + l16;
#pragma unroll
            for (int r = 0; r < 4; r++) {
                int tok = toks[r];
                if (tok >= 0) atomicAdd(out + (size_t)tok * N_OUT + col, acc[i][jj][r]);
            }
        }
    }
}

// ---------------------------------------------------------------------------
extern "C" void kernel_launch(void* const* d_in, const int* in_sizes, int n_in,
                              void* d_out, int out_size, void* d_ws, size_t ws_size,
                              hipStream_t stream) {
    const float* x      = (const float*)d_in[0];
    const float* w_base = (const float*)d_in[1];
    const float* bias   = (const float*)d_in[2];
    const int*   qw_q   = (const int*)d_in[3];
    const int*   qw_k   = (const int*)d_in[4];
    const int*   qw_v   = (const int*)d_in[5];
    const int*   qz_q   = (const int*)d_in[6];
    const int*   qz_k   = (const int*)d_in[7];
    const int*   qz_v   = (const int*)d_in[8];
    const float* sc_q   = (const float*)d_in[9];
    const float* sc_k   = (const float*)d_in[10];
    const float* sc_v   = (const float*)d_in[11];
    const int*   indices= (const int*)d_in[12];
    float* out = (float*)d_out;

    // workspace: wb16 f16[6144][4096] | xp f16[1792][4096] | sArr/uArr f16[4][6144] | perm | pofs
    char* ws = (char*)d_ws;
    __half* wb16 = (__half*)ws;
    size_t wb_bytes = (size_t)N_OUT * K_IN * 2;                   // 50331648
    __half* xp = (__half*)(ws + wb_bytes);
    size_t xp_bytes = (size_t)PM_MAX * K_IN * 2;                  // 14680064
    __half* sArr = (__half*)(ws + wb_bytes + xp_bytes);
    __half* uArr = sArr + (size_t)N_D * N_OUT;
    int* perm = (int*)(uArr + (size_t)N_D * N_OUT);
    int* pofs = perm + PM_MAX;

    build_perm_kernel<<<1, 256, 0, stream>>>(indices, perm, pofs);
    conv_wb_kernel<<<(N_OUT * (K_IN / 8)) / 256, 256, 0, stream>>>(w_base, wb16);
    scaleprep_kernel<<<(N_D * N_OUT) / 256, 256, 0, stream>>>(
        qz_q, qz_k, qz_v, sc_q, sc_k, sc_v, sArr, uArr);
    build_xp_kernel<<<dim3(PM_MAX, 2), 256, 0, stream>>>(x, perm, xp);
    init_out_kernel<<<(T_TOK * N_OUT / 4) / 256, 256, 0, stream>>>(bias, out);
    gemm_kernel<<<NBLK, 512, 0, stream>>>(xp, wb16, qw_q, qw_k, qw_v,
                                          sArr, uArr, perm, pofs, out);
}